// Round 7
// baseline (139.900 us; speedup 1.0000x reference)
//
#include <hip/hip_runtime.h>

#define TSEQ 2048
#define NHEAD 16
#define HD 64
#define CDIM 1024
#define BT 4096  // B*T

typedef unsigned short u16;
typedef __bf16 bf16x8 __attribute__((ext_vector_type(8)));
typedef float f32x4 __attribute__((ext_vector_type(4)));
typedef float f32x16 __attribute__((ext_vector_type(16)));

union Frag {
  int4 i4;
  bf16x8 b;
  u16 u[8];
};

__device__ __forceinline__ u16 f2b(float f) {
  union { float f; unsigned u; } x;
  x.f = f;
  unsigned r = x.u + 0x7fffu + ((x.u >> 16) & 1u);
  return (u16)(r >> 16);
}

// ---------------- fp32 -> bf16 convert (all three inputs, one launch) ----------------
#define N4X 1048576   // x: 4194304 f32
#define N4W1 786432   // Wkqv: 3145728
#define N4W2 262144   // Wproj: 1048576
__global__ void cvt3_kernel(const float* __restrict__ x, const float* __restrict__ w1,
                            const float* __restrict__ w2, u16* __restrict__ ox,
                            u16* __restrict__ o1, u16* __restrict__ o2) {
  int i = blockIdx.x * blockDim.x + threadIdx.x;
  int stride = gridDim.x * blockDim.x;
  for (int idx = i; idx < N4X + N4W1 + N4W2; idx += stride) {
    const float4* src;
    ushort4* dst;
    int k;
    if (idx < N4X) { src = (const float4*)x; dst = (ushort4*)ox; k = idx; }
    else if (idx < N4X + N4W1) { src = (const float4*)w1; dst = (ushort4*)o1; k = idx - N4X; }
    else { src = (const float4*)w2; dst = (ushort4*)o2; k = idx - N4X - N4W1; }
    float4 f = src[k];
    ushort4 o;
    o.x = f2b(f.x); o.y = f2b(f.y); o.z = f2b(f.z); o.w = f2b(f.w);
    dst[k] = o;
  }
}

// ---------------- shared GEMM mainloop (C = A * Bw^T), 128x128 tile ----------------
__device__ __forceinline__ void gload_lds16(const u16* g, u16* l) {
  __builtin_amdgcn_global_load_lds((__attribute__((address_space(1))) void*)g,
                                   (__attribute__((address_space(3))) void*)l, 16, 0, 0);
}

__device__ __forceinline__ void gemm_tiles(const u16* __restrict__ A, const u16* __restrict__ Bw,
                                           int K, int m0, int n0, u16* Ash, u16* Bsh,
                                           f32x4 acc[4][4]) {
  const int tid = threadIdx.x;
  const int lane = tid & 63;
  const int w = tid >> 6;
  const int wr = (w >> 1) * 64, wc = (w & 1) * 64;
  const int lr = lane & 15;
  const int lkb = (lane >> 4) << 3;
  const int r0 = tid >> 2;         // 0..63
  const int c0 = (tid & 3) << 3;   // 0,8,16,24

  for (int k0 = 0; k0 < K; k0 += 32) {
#pragma unroll
    for (int s = 0; s < 2; s++) {
      gload_lds16(&A[(size_t)(m0 + s * 64 + r0) * K + k0 + c0], &Ash[(s * 256 + tid) * 8]);
      gload_lds16(&Bw[(size_t)(n0 + s * 64 + r0) * K + k0 + c0], &Bsh[(s * 256 + tid) * 8]);
    }
    __syncthreads();
    Frag af[4], bfr[4];
#pragma unroll
    for (int i = 0; i < 4; i++) {
      af[i].i4 = *(const int4*)&Ash[(wr + i * 16 + lr) * 32 + lkb];
      bfr[i].i4 = *(const int4*)&Bsh[(wc + i * 16 + lr) * 32 + lkb];
    }
#pragma unroll
    for (int mf = 0; mf < 4; mf++)
#pragma unroll
      for (int nf = 0; nf < 4; nf++)
        acc[mf][nf] = __builtin_amdgcn_mfma_f32_16x16x32_bf16(af[mf].b, bfr[nf].b, acc[mf][nf], 0, 0, 0);
    __syncthreads();
  }
}

// ---------------- GEMM1: kqv = x @ Wkqv^T + b ----------------
// q/k scattered to [bh][t][d]; v^T to [bh][d][c] where c = t with BITS 2<->3 of
// (t&63) swapped — so attention's permuted-kv PV contraction reads contiguous 16B.
__global__ __launch_bounds__(256) void gemm_kqv(const u16* __restrict__ xb, const u16* __restrict__ wb,
                                                const float* __restrict__ bias,
                                                u16* __restrict__ qb, u16* __restrict__ kb,
                                                u16* __restrict__ vtb) {
  __shared__ u16 Ash[128 * 32];
  __shared__ u16 Bsh[128 * 32];
  const int m0 = blockIdx.y * 128, n0 = blockIdx.x * 128;
  f32x4 acc[4][4];
#pragma unroll
  for (int i = 0; i < 4; i++)
#pragma unroll
    for (int j = 0; j < 4; j++) acc[i][j] = (f32x4){0.f, 0.f, 0.f, 0.f};

  gemm_tiles(xb, wb, CDIM, m0, n0, Ash, Bsh, acc);

  const int tid = threadIdx.x;
  const int lane = tid & 63;
  const int w = tid >> 6;
  const int wr = (w >> 1) * 64, wc = (w & 1) * 64;
  const int lr = lane & 15;
  const int rbase = (lane >> 4) << 2;
#pragma unroll
  for (int mf = 0; mf < 4; mf++) {
#pragma unroll
    for (int nf = 0; nf < 4; nf++) {
      f32x4 a = acc[mf][nf];
      int n = n0 + wc + nf * 16 + lr;
      float bval = bias[n];
      int h = n / 192;
      int rem = n - h * 192;
      int s = rem >> 6;
      int d = rem & 63;
      float scale = (s == 1) ? 0.125f : 1.f;  // fold 1/sqrt(64) into q
      u16* dst = (s == 0) ? kb : qb;
#pragma unroll
      for (int r = 0; r < 4; r++) {
        int m = m0 + wr + mf * 16 + rbase + r;
        int bb = m >> 11, tt = m & 2047;
        int bh = (bb << 4) + h;
        u16 val = f2b((a[r] + bval) * scale);
        if (s == 2) {
          int t63 = tt & 63;
          int c = (t63 & 51) | ((t63 & 8) >> 1) | ((t63 & 4) << 1);  // swap bits 2,3
          vtb[((size_t)bh * HD + d) * TSEQ + (tt & ~63) + c] = val;
        } else {
          dst[((size_t)bh * TSEQ + tt) * HD + d] = val;
        }
      }
    }
  }
}

// ---------------- GEMM2: out = y @ Wproj^T + b (fp32 out) ----------------
__global__ __launch_bounds__(256) void gemm_proj(const u16* __restrict__ yb, const u16* __restrict__ wb,
                                                 const float* __restrict__ bias,
                                                 float* __restrict__ out) {
  __shared__ u16 Ash[128 * 32];
  __shared__ u16 Bsh[128 * 32];
  const int m0 = blockIdx.y * 128, n0 = blockIdx.x * 128;
  f32x4 acc[4][4];
#pragma unroll
  for (int i = 0; i < 4; i++)
#pragma unroll
    for (int j = 0; j < 4; j++) acc[i][j] = (f32x4){0.f, 0.f, 0.f, 0.f};

  gemm_tiles(yb, wb, CDIM, m0, n0, Ash, Bsh, acc);

  const int tid = threadIdx.x;
  const int lane = tid & 63;
  const int w = tid >> 6;
  const int wr = (w >> 1) * 64, wc = (w & 1) * 64;
  const int lr = lane & 15;
  const int rbase = (lane >> 4) << 2;
#pragma unroll
  for (int mf = 0; mf < 4; mf++) {
#pragma unroll
    for (int nf = 0; nf < 4; nf++) {
      f32x4 a = acc[mf][nf];
      int n = n0 + wc + nf * 16 + lr;
      float bval = bias[n];
#pragma unroll
      for (int r = 0; r < 4; r++) {
        int m = m0 + wr + mf * 16 + rbase + r;
        out[(size_t)m * CDIM + n] = a[r] + bval;
      }
    }
  }
}

// ---------------- causal flash attention v7: zero-LDS, zero-barrier ----------------
// 1024 blocks x 128 threads (2 independent waves x 32 q-rows; 64-row strip/block).
// S^T = K.Q^T via mfma_32x32x16 with K fragments loaded DIRECT from global
// (same bytes v6 round-tripped through LDS; L1/L2 serve the reuse). No LDS, no
// __syncthreads: every wave runs its own tile chain, latency hidden by TLP
// (all 2048 waves co-resident at t=0). P stays in registers (cvt_pk pack, kv
// contraction order matches the bit2<->3-permuted V^T layout). Fixed-shift
// softmax: per-lane exp+sum only; one lane^32 shuffle at the end.
__global__ __launch_bounds__(128, 3) void attn_kernel(const u16* __restrict__ qb,
                                                      const u16* __restrict__ kb,
                                                      const u16* __restrict__ vtb,
                                                      u16* __restrict__ yb) {
  const int tid = threadIdx.x;
  const int lane = tid & 63;
  const int w = tid >> 6;          // 0..1
  const int l31 = lane & 31;
  const int hi32 = lane >> 5;

  // job decode: bh = jj&31; qs via perm so CU-round-robin groups {g,g+8,g+16,g+24}
  // get qs {31-g, 16+g, 15-g, g} (sum 62); heavy strips dispatched first.
  const int jj = blockIdx.x;
  const int bh = jj & 31;
  const int s = jj >> 5;           // 0..31
  const int g = s & 7, sel = s >> 3;
  const int qs = (sel == 0) ? 31 - g : (sel == 1) ? 16 + g : (sel == 2) ? 15 - g : g;
  const int q0w = qs * 64 + w * 32;
  const int nt = qs + 1;
  const int qg = q0w + l31;        // this lane's q row

  const u16* Qp = qb + (size_t)bh * TSEQ * HD;
  const u16* Kp = kb + (size_t)bh * TSEQ * HD;
  const u16* Vt = vtb + (size_t)bh * HD * TSEQ;

  // Q B-frags (4 k-steps of 16) in registers for the whole job
  Frag qf[4];
#pragma unroll
  for (int k = 0; k < 4; k++)
    qf[k].i4 = *(const int4*)&Qp[(size_t)(q0w + l31) * HD + k * 16 + hi32 * 8];

  f32x16 O0, O1;
  float lp = 0.f;
#pragma unroll
  for (int i = 0; i < 16; i++) { O0[i] = 0.f; O1[i] = 0.f; }

  for (int j = 0; j < nt; j++) {
    const int kv0 = j * 64;
    const bool nt1run = (kv0 + 32 <= q0w + 31);  // wave-uniform

    // K A-frags direct from global: lane l31 reads row kv0+l31 (and +32),
    // 16B at k*16 + hi32*8 — the exact bytes v6 staged through LDS.
    Frag ka[4], kc[4];
#pragma unroll
    for (int k = 0; k < 4; k++)
      ka[k].i4 = *(const int4*)&Kp[(size_t)(kv0 + l31) * HD + k * 16 + hi32 * 8];
    if (nt1run) {
#pragma unroll
      for (int k = 0; k < 4; k++)
        kc[k].i4 = *(const int4*)&Kp[(size_t)(kv0 + 32 + l31) * HD + k * 16 + hi32 * 8];
    }
    // V B-frags direct from global (permuted layout -> contiguous 16B); issued
    // early so their latency hides under the S MFMAs + softmax.
    Frag vf0[4], vf1[4];
#pragma unroll
    for (int k = 0; k < 4; k++) {
      vf0[k].i4 = *(const int4*)&Vt[(size_t)l31 * TSEQ + kv0 + (k * 2 + hi32) * 8];
      vf1[k].i4 = *(const int4*)&Vt[(size_t)(32 + l31) * TSEQ + kv0 + (k * 2 + hi32) * 8];
    }

    // S^T = K Q^T  (two 32-kv halves)
    f32x16 S0, S1;
#pragma unroll
    for (int i = 0; i < 16; i++) { S0[i] = 0.f; S1[i] = 0.f; }
    __builtin_amdgcn_s_setprio(1);
#pragma unroll
    for (int k = 0; k < 4; k++)
      S0 = __builtin_amdgcn_mfma_f32_32x32x16_bf16(ka[k].b, qf[k].b, S0, 0, 0, 0);
    if (nt1run) {
#pragma unroll
      for (int k = 0; k < 4; k++)
        S1 = __builtin_amdgcn_mfma_f32_32x32x16_bf16(kc[k].b, qf[k].b, S1, 0, 0, 0);
    }
    __builtin_amdgcn_s_setprio(0);

    // fixed-shift softmax: P = exp(S) (masked on diagonal tile), per-lane row sum
    if (j == nt - 1) {
#pragma unroll
      for (int reg = 0; reg < 16; reg++) {
        int crow = (reg & 3) + 8 * (reg >> 2) + 4 * hi32;
        S0[reg] = (kv0 + crow <= qg) ? __expf(S0[reg]) : 0.f;
        S1[reg] = (kv0 + 32 + crow <= qg) ? __expf(S1[reg]) : 0.f;
      }
    } else {
#pragma unroll
      for (int reg = 0; reg < 16; reg++) {
        S0[reg] = __expf(S0[reg]);
        S1[reg] = __expf(S1[reg]);
      }
    }
#pragma unroll
    for (int reg = 0; reg < 16; reg++) lp += S0[reg] + S1[reg];

    // pack P into A-frags in the lane's own kv order (no cross-lane movement)
    Frag pa[4];
#define PACK(dst, SV, base)                                                          \
    asm("v_cvt_pk_bf16_f32 %0, %1, %2" : "=v"(dst.i4.x) : "v"(SV[base + 0]), "v"(SV[base + 1])); \
    asm("v_cvt_pk_bf16_f32 %0, %1, %2" : "=v"(dst.i4.y) : "v"(SV[base + 2]), "v"(SV[base + 3])); \
    asm("v_cvt_pk_bf16_f32 %0, %1, %2" : "=v"(dst.i4.z) : "v"(SV[base + 4]), "v"(SV[base + 5])); \
    asm("v_cvt_pk_bf16_f32 %0, %1, %2" : "=v"(dst.i4.w) : "v"(SV[base + 6]), "v"(SV[base + 7]));
    PACK(pa[0], S0, 0)
    PACK(pa[1], S0, 8)
    PACK(pa[2], S1, 0)
    PACK(pa[3], S1, 8)
#undef PACK

    // O += P V (A = pa regs, B = vf regs)
    __builtin_amdgcn_s_setprio(1);
#pragma unroll
    for (int k = 0; k < 2; k++) {
      O0 = __builtin_amdgcn_mfma_f32_32x32x16_bf16(pa[k].b, vf0[k].b, O0, 0, 0, 0);
      O1 = __builtin_amdgcn_mfma_f32_32x32x16_bf16(pa[k].b, vf1[k].b, O1, 0, 0, 0);
    }
    if (nt1run) {
#pragma unroll
      for (int k = 2; k < 4; k++) {
        O0 = __builtin_amdgcn_mfma_f32_32x32x16_bf16(pa[k].b, vf0[k].b, O0, 0, 0, 0);
        O1 = __builtin_amdgcn_mfma_f32_32x32x16_bf16(pa[k].b, vf1[k].b, O1, 0, 0, 0);
      }
    }
    __builtin_amdgcn_s_setprio(0);
  }

  // row sums: lane^32 partner holds the other kv half of the same q row
  float lpt = lp + __shfl_xor(lp, 32);
  const int b = bh >> 4, h = bh & 15;
#pragma unroll
  for (int reg = 0; reg < 16; reg++) {
    int qlocal = (reg & 3) + 8 * (reg >> 2) + 4 * hi32;
    float invr = 1.f / __shfl(lpt, qlocal);
    int t = q0w + qlocal;
    size_t rowoff = ((size_t)(b * TSEQ + t) << 10) + (h << 6);
    yb[rowoff + l31] = f2b(O0[reg] * invr);
    yb[rowoff + 32 + l31] = f2b(O1[reg] * invr);
  }
}

extern "C" void kernel_launch(void* const* d_in, const int* in_sizes, int n_in,
                              void* d_out, int out_size, void* d_ws, size_t ws_size,
                              hipStream_t stream) {
  const float* x = (const float*)d_in[0];
  const float* Wkqv = (const float*)d_in[1];
  const float* bkqv = (const float*)d_in[2];
  const float* Wproj = (const float*)d_in[3];
  const float* bproj = (const float*)d_in[4];
  float* out = (float*)d_out;

  u16* ws = (u16*)d_ws;
  u16* xb = ws;                       // 4194304
  u16* wkqvb = xb + 4194304;          // 3145728
  u16* wprojb = wkqvb + 3145728;      // 1048576
  u16* qb = wprojb + 1048576;         // 4194304
  u16* kb = qb + 4194304;             // 4194304
  u16* vtb = kb + 4194304;            // 4194304 ([bh][d][t], cols bit-2/3 swapped per 64)
  u16* yb = vtb + 4194304;            // 4194304  (total 48 MB)

  cvt3_kernel<<<2048, 256, 0, stream>>>(x, Wkqv, Wproj, xb, wkqvb, wprojb);
  gemm_kqv<<<dim3(24, 32), 256, 0, stream>>>(xb, wkqvb, bkqv, qb, kb, vtb);
  attn_kernel<<<1024, 128, 0, stream>>>(qb, kb, vtb, yb);
  gemm_proj<<<dim3(8, 32), 256, 0, stream>>>(yb, wprojb, bproj, out);
}

// Round 8
// 138.968 us; speedup vs baseline: 1.0067x; 1.0067x over previous
//
#include <hip/hip_runtime.h>

#define TSEQ 2048
#define NHEAD 16
#define HD 64
#define CDIM 1024
#define BT 4096  // B*T

typedef unsigned short u16;
typedef __bf16 bf16x8 __attribute__((ext_vector_type(8)));
typedef float f32x4 __attribute__((ext_vector_type(4)));
typedef float f32x16 __attribute__((ext_vector_type(16)));

union Frag {
  int4 i4;
  bf16x8 b;
  u16 u[8];
};

__device__ __forceinline__ u16 f2b(float f) {
  union { float f; unsigned u; } x;
  x.f = f;
  unsigned r = x.u + 0x7fffu + ((x.u >> 16) & 1u);
  return (u16)(r >> 16);
}

// ---------------- fp32 -> bf16 convert (all three inputs, one launch) ----------------
#define N4X 1048576   // x: 4194304 f32
#define N4W1 786432   // Wkqv: 3145728
#define N4W2 262144   // Wproj: 1048576
__global__ void cvt3_kernel(const float* __restrict__ x, const float* __restrict__ w1,
                            const float* __restrict__ w2, u16* __restrict__ ox,
                            u16* __restrict__ o1, u16* __restrict__ o2) {
  int i = blockIdx.x * blockDim.x + threadIdx.x;
  int stride = gridDim.x * blockDim.x;
  for (int idx = i; idx < N4X + N4W1 + N4W2; idx += stride) {
    const float4* src;
    ushort4* dst;
    int k;
    if (idx < N4X) { src = (const float4*)x; dst = (ushort4*)ox; k = idx; }
    else if (idx < N4X + N4W1) { src = (const float4*)w1; dst = (ushort4*)o1; k = idx - N4X; }
    else { src = (const float4*)w2; dst = (ushort4*)o2; k = idx - N4X - N4W1; }
    float4 f = src[k];
    ushort4 o;
    o.x = f2b(f.x); o.y = f2b(f.y); o.z = f2b(f.z); o.w = f2b(f.w);
    dst[k] = o;
  }
}

// ---------------- shared GEMM mainloop (C = A * Bw^T), 128x128 tile ----------------
__device__ __forceinline__ void gload_lds16(const u16* g, u16* l) {
  __builtin_amdgcn_global_load_lds((__attribute__((address_space(1))) void*)g,
                                   (__attribute__((address_space(3))) void*)l, 16, 0, 0);
}

__device__ __forceinline__ void gemm_tiles(const u16* __restrict__ A, const u16* __restrict__ Bw,
                                           int K, int m0, int n0, u16* Ash, u16* Bsh,
                                           f32x4 acc[4][4]) {
  const int tid = threadIdx.x;
  const int lane = tid & 63;
  const int w = tid >> 6;
  const int wr = (w >> 1) * 64, wc = (w & 1) * 64;
  const int lr = lane & 15;
  const int lkb = (lane >> 4) << 3;
  const int r0 = tid >> 2;         // 0..63
  const int c0 = (tid & 3) << 3;   // 0,8,16,24

  for (int k0 = 0; k0 < K; k0 += 32) {
#pragma unroll
    for (int s = 0; s < 2; s++) {
      gload_lds16(&A[(size_t)(m0 + s * 64 + r0) * K + k0 + c0], &Ash[(s * 256 + tid) * 8]);
      gload_lds16(&Bw[(size_t)(n0 + s * 64 + r0) * K + k0 + c0], &Bsh[(s * 256 + tid) * 8]);
    }
    __syncthreads();
    Frag af[4], bfr[4];
#pragma unroll
    for (int i = 0; i < 4; i++) {
      af[i].i4 = *(const int4*)&Ash[(wr + i * 16 + lr) * 32 + lkb];
      bfr[i].i4 = *(const int4*)&Bsh[(wc + i * 16 + lr) * 32 + lkb];
    }
#pragma unroll
    for (int mf = 0; mf < 4; mf++)
#pragma unroll
      for (int nf = 0; nf < 4; nf++)
        acc[mf][nf] = __builtin_amdgcn_mfma_f32_16x16x32_bf16(af[mf].b, bfr[nf].b, acc[mf][nf], 0, 0, 0);
    __syncthreads();
  }
}

// ---------------- GEMM1: kqv = x @ Wkqv^T + b ----------------
// q/k scattered to [bh][t][d]; v^T to [bh][d][c] where c = t with BITS 2<->3 of
// (t&63) swapped — so attention's permuted-kv PV contraction reads contiguous 16B.
__global__ __launch_bounds__(256) void gemm_kqv(const u16* __restrict__ xb, const u16* __restrict__ wb,
                                                const float* __restrict__ bias,
                                                u16* __restrict__ qb, u16* __restrict__ kb,
                                                u16* __restrict__ vtb) {
  __shared__ u16 Ash[128 * 32];
  __shared__ u16 Bsh[128 * 32];
  const int m0 = blockIdx.y * 128, n0 = blockIdx.x * 128;
  f32x4 acc[4][4];
#pragma unroll
  for (int i = 0; i < 4; i++)
#pragma unroll
    for (int j = 0; j < 4; j++) acc[i][j] = (f32x4){0.f, 0.f, 0.f, 0.f};

  gemm_tiles(xb, wb, CDIM, m0, n0, Ash, Bsh, acc);

  const int tid = threadIdx.x;
  const int lane = tid & 63;
  const int w = tid >> 6;
  const int wr = (w >> 1) * 64, wc = (w & 1) * 64;
  const int lr = lane & 15;
  const int rbase = (lane >> 4) << 2;
#pragma unroll
  for (int mf = 0; mf < 4; mf++) {
#pragma unroll
    for (int nf = 0; nf < 4; nf++) {
      f32x4 a = acc[mf][nf];
      int n = n0 + wc + nf * 16 + lr;
      float bval = bias[n];
      int h = n / 192;
      int rem = n - h * 192;
      int s = rem >> 6;
      int d = rem & 63;
      float scale = (s == 1) ? 0.125f : 1.f;  // fold 1/sqrt(64) into q
      u16* dst = (s == 0) ? kb : qb;
#pragma unroll
      for (int r = 0; r < 4; r++) {
        int m = m0 + wr + mf * 16 + rbase + r;
        int bb = m >> 11, tt = m & 2047;
        int bh = (bb << 4) + h;
        u16 val = f2b((a[r] + bval) * scale);
        if (s == 2) {
          int t63 = tt & 63;
          int c = (t63 & 51) | ((t63 & 8) >> 1) | ((t63 & 4) << 1);  // swap bits 2,3
          vtb[((size_t)bh * HD + d) * TSEQ + (tt & ~63) + c] = val;
        } else {
          dst[((size_t)bh * TSEQ + tt) * HD + d] = val;
        }
      }
    }
  }
}

// ---------------- GEMM2: out = y @ Wproj^T + b (fp32 out) ----------------
__global__ __launch_bounds__(256) void gemm_proj(const u16* __restrict__ yb, const u16* __restrict__ wb,
                                                 const float* __restrict__ bias,
                                                 float* __restrict__ out) {
  __shared__ u16 Ash[128 * 32];
  __shared__ u16 Bsh[128 * 32];
  const int m0 = blockIdx.y * 128, n0 = blockIdx.x * 128;
  f32x4 acc[4][4];
#pragma unroll
  for (int i = 0; i < 4; i++)
#pragma unroll
    for (int j = 0; j < 4; j++) acc[i][j] = (f32x4){0.f, 0.f, 0.f, 0.f};

  gemm_tiles(yb, wb, CDIM, m0, n0, Ash, Bsh, acc);

  const int tid = threadIdx.x;
  const int lane = tid & 63;
  const int w = tid >> 6;
  const int wr = (w >> 1) * 64, wc = (w & 1) * 64;
  const int lr = lane & 15;
  const int rbase = (lane >> 4) << 2;
#pragma unroll
  for (int mf = 0; mf < 4; mf++) {
#pragma unroll
    for (int nf = 0; nf < 4; nf++) {
      f32x4 a = acc[mf][nf];
      int n = n0 + wc + nf * 16 + lr;
      float bval = bias[n];
#pragma unroll
      for (int r = 0; r < 4; r++) {
        int m = m0 + wr + mf * 16 + rbase + r;
        out[(size_t)m * CDIM + n] = a[r] + bval;
      }
    }
  }
}

// ---------------- causal flash attention v8: split-KV, lean waves ----------------
// 2048 blocks x 128 threads. Block = (bh, 32-row q-strip); its TWO waves split the
// KV range (wave w takes 32-wide tiles j%2==w) and merge partials once via LDS —
// valid because fixed-shift softmax is additive over KV. 32-wide tiles keep the
// per-wave register footprint lean (target <=128 VGPR -> 16 waves/CU). No barriers
// in the loop; K/V loaded direct from global (L1/L2-served: all 8 blocks on a CU
// share the same bh stream). P stays in registers (cvt_pk pack; kv contraction
// order matches the bit2<->3-permuted V^T layout).
__global__ __launch_bounds__(128, 3) void attn_kernel(const u16* __restrict__ qb,
                                                      const u16* __restrict__ kb,
                                                      const u16* __restrict__ vtb,
                                                      u16* __restrict__ yb) {
  __shared__ float Osh[64][33];  // wave-1 partial O (padded: conflict-free)
  __shared__ float lsh[64];      // wave-1 partial row sums

  const int tid = threadIdx.x;
  const int lane = tid & 63;
  const int w = tid >> 6;          // 0..1 (KV-half owner)
  const int l31 = lane & 31;
  const int hi32 = lane >> 5;

  // job decode: bh = jj&31 (same for the whole stride-256 CU group);
  // class r = jj>>5 in [0,64) -> strip s via perm so each CU group's 8 classes
  // {c,c+8,..,c+56} get s = {63-c, 48+c, 47-c, 32+c, 31-c, 16+c, 15-c, c}
  // (sum 252 -> balanced); heavy strips dispatched first.
  const int jj = blockIdx.x;
  const int bh = jj & 31;
  const int r = jj >> 5;
  const int g = r & 7, sel = r >> 3;
  int s;
  switch (sel) {
    case 0: s = 63 - g; break;
    case 1: s = 48 + g; break;
    case 2: s = 47 - g; break;
    case 3: s = 32 + g; break;
    case 4: s = 31 - g; break;
    case 5: s = 16 + g; break;
    case 6: s = 15 - g; break;
    default: s = g; break;
  }
  const int q0w = s * 32;
  const int nt32 = s + 1;          // 32-wide KV tiles
  const int qg = q0w + l31;        // this lane's q row

  const u16* Qp = qb + (size_t)bh * TSEQ * HD;
  const u16* Kp = kb + (size_t)bh * TSEQ * HD;
  const u16* Vt = vtb + (size_t)bh * HD * TSEQ;

  // Q B-frags (4 d-steps of 16) in registers for the whole job
  Frag qf[4];
#pragma unroll
  for (int k = 0; k < 4; k++)
    qf[k].i4 = *(const int4*)&Qp[(size_t)(q0w + l31) * HD + k * 16 + hi32 * 8];

  f32x16 O0, O1;
  float lp = 0.f;
#pragma unroll
  for (int i = 0; i < 16; i++) { O0[i] = 0.f; O1[i] = 0.f; }

  for (int j = w; j < nt32; j += 2) {
    const int kv0 = j * 32;

    // K A-frags + V B-frags direct from global (independent; compiler overlaps)
    Frag ka[4], vf0[2], vf1[2];
#pragma unroll
    for (int k = 0; k < 4; k++)
      ka[k].i4 = *(const int4*)&Kp[(size_t)(kv0 + l31) * HD + k * 16 + hi32 * 8];
#pragma unroll
    for (int k = 0; k < 2; k++) {
      vf0[k].i4 = *(const int4*)&Vt[(size_t)l31 * TSEQ + kv0 + (k * 2 + hi32) * 8];
      vf1[k].i4 = *(const int4*)&Vt[(size_t)(32 + l31) * TSEQ + kv0 + (k * 2 + hi32) * 8];
    }

    // S^T = K Q^T (32 kv x 32 q)
    f32x16 S0;
#pragma unroll
    for (int i = 0; i < 16; i++) S0[i] = 0.f;
    __builtin_amdgcn_s_setprio(1);
#pragma unroll
    for (int k = 0; k < 4; k++)
      S0 = __builtin_amdgcn_mfma_f32_32x32x16_bf16(ka[k].b, qf[k].b, S0, 0, 0, 0);
    __builtin_amdgcn_s_setprio(0);

    // fixed-shift softmax: P = exp(S) (masked on the diagonal tile)
    if (j == nt32 - 1) {
#pragma unroll
      for (int reg = 0; reg < 16; reg++) {
        int crow = (reg & 3) + 8 * (reg >> 2) + 4 * hi32;
        S0[reg] = (kv0 + crow <= qg) ? __expf(S0[reg]) : 0.f;
      }
    } else {
#pragma unroll
      for (int reg = 0; reg < 16; reg++) S0[reg] = __expf(S0[reg]);
    }
#pragma unroll
    for (int reg = 0; reg < 16; reg++) lp += S0[reg];

    // pack P into A-frags in the lane's own kv order (no cross-lane movement)
    Frag pa[2];
#define PACK(dst, SV, base)                                                          \
    asm("v_cvt_pk_bf16_f32 %0, %1, %2" : "=v"(dst.i4.x) : "v"(SV[base + 0]), "v"(SV[base + 1])); \
    asm("v_cvt_pk_bf16_f32 %0, %1, %2" : "=v"(dst.i4.y) : "v"(SV[base + 2]), "v"(SV[base + 3])); \
    asm("v_cvt_pk_bf16_f32 %0, %1, %2" : "=v"(dst.i4.z) : "v"(SV[base + 4]), "v"(SV[base + 5])); \
    asm("v_cvt_pk_bf16_f32 %0, %1, %2" : "=v"(dst.i4.w) : "v"(SV[base + 6]), "v"(SV[base + 7]));
    PACK(pa[0], S0, 0)
    PACK(pa[1], S0, 8)
#undef PACK

    // O += P V
    __builtin_amdgcn_s_setprio(1);
#pragma unroll
    for (int k = 0; k < 2; k++) {
      O0 = __builtin_amdgcn_mfma_f32_32x32x16_bf16(pa[k].b, vf0[k].b, O0, 0, 0, 0);
      O1 = __builtin_amdgcn_mfma_f32_32x32x16_bf16(pa[k].b, vf1[k].b, O1, 0, 0, 0);
    }
    __builtin_amdgcn_s_setprio(0);
  }

  // intra-wave k-half reduce (lane^32 partner covers the other kv offsets)
  float lpw = lp + __shfl_xor(lp, 32);

  // cross-wave merge: additive (fixed-shift) -> one LDS round trip
  if (w == 1) {
#pragma unroll
    for (int reg = 0; reg < 16; reg++) {
      Osh[lane][reg] = O0[reg];
      Osh[lane][16 + reg] = O1[reg];
    }
    lsh[lane] = lpw;
  }
  __syncthreads();
  if (w == 0) {
#pragma unroll
    for (int reg = 0; reg < 16; reg++) {
      O0[reg] += Osh[lane][reg];
      O1[reg] += Osh[lane][16 + reg];
    }
    float ltot = lpw + lsh[lane];
    const int b = bh >> 4, h = bh & 15;
#pragma unroll
    for (int reg = 0; reg < 16; reg++) {
      int qlocal = (reg & 3) + 8 * (reg >> 2) + 4 * hi32;
      float invr = 1.f / __shfl(ltot, qlocal);
      int t = q0w + qlocal;
      size_t rowoff = ((size_t)(b * TSEQ + t) << 10) + (h << 6);
      yb[rowoff + l31] = f2b(O0[reg] * invr);
      yb[rowoff + 32 + l31] = f2b(O1[reg] * invr);
    }
  }
}

extern "C" void kernel_launch(void* const* d_in, const int* in_sizes, int n_in,
                              void* d_out, int out_size, void* d_ws, size_t ws_size,
                              hipStream_t stream) {
  const float* x = (const float*)d_in[0];
  const float* Wkqv = (const float*)d_in[1];
  const float* bkqv = (const float*)d_in[2];
  const float* Wproj = (const float*)d_in[3];
  const float* bproj = (const float*)d_in[4];
  float* out = (float*)d_out;

  u16* ws = (u16*)d_ws;
  u16* xb = ws;                       // 4194304
  u16* wkqvb = xb + 4194304;          // 3145728
  u16* wprojb = wkqvb + 3145728;      // 1048576
  u16* qb = wprojb + 1048576;         // 4194304
  u16* kb = qb + 4194304;             // 4194304
  u16* vtb = kb + 4194304;            // 4194304 ([bh][d][t], cols bit-2/3 swapped per 64)
  u16* yb = vtb + 4194304;            // 4194304  (total 48 MB)

  cvt3_kernel<<<2048, 256, 0, stream>>>(x, Wkqv, Wproj, xb, wkqvb, wprojb);
  gemm_kqv<<<dim3(24, 32), 256, 0, stream>>>(xb, wkqvb, bkqv, qb, kb, vtb);
  attn_kernel<<<2048, 128, 0, stream>>>(qb, kb, vtb, yb);
  gemm_proj<<<dim3(8, 32), 256, 0, stream>>>(yb, wprojb, bproj, out);
}